// Round 10
// baseline (216.178 us; speedup 1.0000x reference)
//
#include <hip/hip_runtime.h>

// MQA: B=2, S=2048, HID=2048, H=16, D=128 (single KV head), causal.
// Pipeline: cast -> fused QKV NT-GEMM (pipelined, counted-vmcnt) -> V
//           transpose -> kmax -> flash attention (32x32x16, in-register P,
//           triple-buffered KVBLK=32, counted vmcnt) -> out NT-GEMM.

#define S_LEN 2048
#define HID_  2048
#define D_    128
#define NQKV  2304   // 2048 Q + 128 K + 128 V columns

typedef __attribute__((ext_vector_type(8))) short bf16x8;
typedef __attribute__((ext_vector_type(4))) float f32x4;
typedef __attribute__((ext_vector_type(16))) float f32x16;

__device__ __forceinline__ unsigned short f2b(float f) {
  union { float f; unsigned int u; } a; a.f = f;
  unsigned int u = a.u;
  return (unsigned short)((u + 0x7fffu + ((u >> 16) & 1u)) >> 16);  // RNE
}

__device__ __forceinline__ float b2f(unsigned short s) {
  union { unsigned int u; float f; } a; a.u = ((unsigned int)s) << 16;
  return a.f;
}

__device__ __forceinline__ void load_lds16(const void* g, void* l) {
  __builtin_amdgcn_global_load_lds(
      (const __attribute__((address_space(1))) void*)g,
      (__attribute__((address_space(3))) void*)l, 16, 0, 0);
}

__device__ __forceinline__ f32x4 mfma16(bf16x8 a, bf16x8 b, f32x4 c) {
  return __builtin_amdgcn_mfma_f32_16x16x32_bf16(a, b, c, 0, 0, 0);
}

__device__ __forceinline__ f32x16 mfma32(bf16x8 a, bf16x8 b, f32x16 c) {
  return __builtin_amdgcn_mfma_f32_32x32x16_bf16(a, b, c, 0, 0, 0);
}

__device__ __forceinline__ unsigned int cvtpk(float lo, float hi) {
  unsigned int r;
  asm volatile("v_cvt_pk_bf16_f32 %0, %1, %2" : "=v"(r) : "v"(lo), "v"(hi));
  return r;
}

// ---------------- casts / packing ----------------

__global__ void cast_f32_bf16_k(const float* __restrict__ in,
                                unsigned short* __restrict__ out, int n4) {
  const int idx = blockIdx.x * 256 + threadIdx.x;
  if (idx < n4) {
    const float4 v = ((const float4*)in)[idx];
    ushort4 o;
    o.x = f2b(v.x); o.y = f2b(v.y); o.z = f2b(v.z); o.w = f2b(v.w);
    ((ushort4*)out)[idx] = o;
  }
}

__global__ void build_wcat_k(const float* __restrict__ Wq,
                             const float* __restrict__ Wk,
                             const float* __restrict__ Wv,
                             const float* __restrict__ bq,
                             const float* __restrict__ bk,
                             const float* __restrict__ bv,
                             unsigned short* __restrict__ Wcat,
                             float* __restrict__ bcat,
                             float* __restrict__ Kmax) {
  const int idx = blockIdx.x * 256 + threadIdx.x;
  const int i = idx * 4;
  const int row = i >> 11;
  const int col = i & 2047;
  const float* src;
  if (row < 2048)      src = Wq + (size_t)row * 2048 + col;
  else if (row < 2176) src = Wk + (size_t)(row - 2048) * 2048 + col;
  else                 src = Wv + (size_t)(row - 2176) * 2048 + col;
  const float4 v = *(const float4*)src;
  ushort4 o;
  o.x = f2b(v.x); o.y = f2b(v.y); o.z = f2b(v.z); o.w = f2b(v.w);
  *(ushort4*)(Wcat + i) = o;
  if (idx < NQKV)
    bcat[idx] = (idx < 2048) ? bq[idx] : (idx < 2176) ? bk[idx - 2048] : bv[idx - 2176];
  if (idx < 2) Kmax[idx] = 0.f;   // re-init every launch (runs before kmax_k)
}

// Vt[b][d][s] = QKV[b*S+s][2176+d] -- LDS-tiled transpose
__global__ __launch_bounds__(256)
void transpose_v(const unsigned short* __restrict__ QKV,
                 unsigned short* __restrict__ Vt) {
  __shared__ unsigned short tile[64][136];
  const int tid = threadIdx.x;
  const int s0  = blockIdx.x * 64;
  const int b   = blockIdx.y;
  const int row = tid >> 2;
  const int cb  = (tid & 3) * 32;
  const unsigned short* src = QKV + (size_t)(b * S_LEN + s0 + row) * NQKV + 2176 + cb;
#pragma unroll
  for (int i = 0; i < 4; ++i)
    *(bf16x8*)&tile[row][cb + i * 8] = *(const bf16x8*)(src + i * 8);
  __syncthreads();
  const int d  = tid >> 1;
  const int sc = (tid & 1) * 32;
  unsigned short* dst = Vt + ((size_t)b * D_ + d) * S_LEN + s0 + sc;
#pragma unroll
  for (int i = 0; i < 4; ++i) {
    bf16x8 vv;
#pragma unroll
    for (int e = 0; e < 8; ++e) vv[e] = tile[sc + i * 8 + e][d];
    *(bf16x8*)(dst + i * 8) = vv;
  }
}

// max_s ||k[b,s]||^2 -> Kmax[b] (as float bits via atomicMax on uint)
__global__ __launch_bounds__(256)
void kmax_k(const unsigned short* __restrict__ QKV, float* __restrict__ Kmax) {
  __shared__ float red[256];
  const int tid = threadIdx.x;
  const int b = blockIdx.x >> 3;
  const int s = (blockIdx.x & 7) * 256 + tid;
  const unsigned short* kp = QKV + (size_t)(b * S_LEN + s) * NQKV + 2048;
  float sum = 0.f;
#pragma unroll
  for (int i = 0; i < 16; ++i) {
    bf16x8 v = *(const bf16x8*)(kp + i * 8);
#pragma unroll
    for (int e = 0; e < 8; ++e) { const float f = b2f((unsigned short)v[e]); sum += f * f; }
  }
  red[tid] = sum;
  __syncthreads();
  for (int off = 128; off > 0; off >>= 1) {
    if (tid < off) red[tid] = fmaxf(red[tid], red[tid + off]);
    __syncthreads();
  }
  if (tid == 0) atomicMax((unsigned int*)(Kmax + b), __float_as_uint(red[0]));
}

// ---------------- pipelined NT GEMM (unchanged from R8) ----------------

template <int OUT_F32, int NJ>
__global__ __launch_bounds__(512, 2)
void gemm_nt2(const unsigned short* __restrict__ A,
              const unsigned short* __restrict__ Bm,
              const float* __restrict__ bias,
              void* __restrict__ Cv,
              int N, int K) {
  constexpr int BN = 64 * NJ;
  __shared__ __align__(16) char As[3][128 * 128];   // [buf][row<<7 | slot*16]
  __shared__ __align__(16) char Bs[3][BN * 128];

  const int tid  = threadIdx.x;
  const int lane = tid & 63;
  const int wv   = tid >> 6;
  const int wr   = wv >> 2;        // 0..1
  const int wc   = wv & 3;         // 0..3
  const int g    = lane >> 4, r = lane & 15;

  const int nwg  = gridDim.x;
  const int bid  = blockIdx.x;
  const int sbid = (bid & 7) * (nwg >> 3) + (bid >> 3);   // XCD-chunked
  const int nx   = N / BN;
  const int m0   = (sbid / nx) * 128;
  const int n0   = (sbid % nx) * BN;
  const int NT   = K >> 6;

  const size_t Kb = (size_t)K * 2;
  const char* Ab = (const char*)A + (size_t)m0 * Kb;
  const char* Bb = (const char*)Bm + (size_t)n0 * Kb;

#define STAGE_A(bufi, t)                                                       \
  {                                                                            \
    const int kb_ = (t) * 128;                                                 \
    _Pragma("unroll")                                                          \
    for (int i_ = 0; i_ < 2; ++i_) {                                           \
      const int ch_ = tid + 512 * i_;                                          \
      const int rr_ = ch_ >> 3;                                                \
      const int sl_ = (ch_ & 7) ^ (rr_ & 7);                                   \
      load_lds16(Ab + (size_t)rr_ * Kb + kb_ + sl_ * 16, As[bufi] + ch_ * 16); \
    }                                                                          \
  }
#define STAGE_B(bufi, t)                                                       \
  {                                                                            \
    const int kb_ = (t) * 128;                                                 \
    _Pragma("unroll")                                                          \
    for (int i_ = 0; i_ < NJ; ++i_) {                                          \
      const int ch_ = tid + 512 * i_;                                          \
      const int rr_ = ch_ >> 3;                                                \
      const int sl_ = (ch_ & 7) ^ (rr_ & 7);                                   \
      load_lds16(Bb + (size_t)rr_ * Kb + kb_ + sl_ * 16, Bs[bufi] + ch_ * 16); \
    }                                                                          \
  }

  f32x4 acc[4][NJ] = {};
  const int s0 = ((g ^ (r & 7)) << 4);           // kk=0 slot byte
  const int s1 = (((4 | g) ^ (r & 7)) << 4);     // kk=1 slot byte

  STAGE_A(0, 0) STAGE_B(0, 0) STAGE_A(1, 1) STAGE_B(1, 1)

  // publish buf0 before the t=0 reads (R8 fix)
  asm volatile("s_waitcnt vmcnt(%0)" :: "i"(NJ + 2) : "memory");
  __builtin_amdgcn_s_barrier();
  __builtin_amdgcn_sched_barrier(0);

  for (int t = 0; t < NT; ++t) {
    const char* as = As[t % 3];
    const char* bs = Bs[t % 3];
    const int nb = (t + 2) % 3;
    const bool pf = (t + 2 < NT);

    bf16x8 af[4], bfr[NJ];
    // ---- phase 0 (kk = 0) ----
#pragma unroll
    for (int i = 0; i < 4; ++i)
      af[i] = *(const bf16x8*)(as + ((wr * 64 + i * 16 + r) << 7) + s0);
#pragma unroll
    for (int j = 0; j < NJ; ++j)
      bfr[j] = *(const bf16x8*)(bs + ((wc * 16 * NJ + j * 16 + r) << 7) + s0);
    if (pf) STAGE_A(nb, t + 2)
    __builtin_amdgcn_s_barrier();
    __builtin_amdgcn_sched_barrier(0);
    asm volatile("s_waitcnt lgkmcnt(0)" ::: "memory");
    __builtin_amdgcn_sched_barrier(0);
    __builtin_amdgcn_s_setprio(1);
#pragma unroll
    for (int i = 0; i < 4; ++i)
#pragma unroll
      for (int j = 0; j < NJ; ++j)
        acc[i][j] = mfma16(af[i], bfr[j], acc[i][j]);
    __builtin_amdgcn_s_setprio(0);
    __builtin_amdgcn_sched_barrier(0);

    // ---- phase 1 (kk = 1) ----
#pragma unroll
    for (int i = 0; i < 4; ++i)
      af[i] = *(const bf16x8*)(as + ((wr * 64 + i * 16 + r) << 7) + s1);
#pragma unroll
    for (int j = 0; j < NJ; ++j)
      bfr[j] = *(const bf16x8*)(bs + ((wc * 16 * NJ + j * 16 + r) << 7) + s1);
    if (pf) STAGE_B(nb, t + 2)
    __builtin_amdgcn_s_barrier();
    __builtin_amdgcn_sched_barrier(0);
    asm volatile("s_waitcnt lgkmcnt(0)" ::: "memory");
    __builtin_amdgcn_sched_barrier(0);
    __builtin_amdgcn_s_setprio(1);
#pragma unroll
    for (int i = 0; i < 4; ++i)
#pragma unroll
      for (int j = 0; j < NJ; ++j)
        acc[i][j] = mfma16(af[i], bfr[j], acc[i][j]);
    __builtin_amdgcn_s_setprio(0);

    // ---- tile boundary: publish buf t+1 (counted vmcnt, never 0 mid-loop) --
    if (pf) { asm volatile("s_waitcnt vmcnt(%0)" :: "i"(NJ + 2) : "memory"); }
    else    { asm volatile("s_waitcnt vmcnt(0)" ::: "memory"); }
    __builtin_amdgcn_s_barrier();
    __builtin_amdgcn_sched_barrier(0);
  }

  // epilogue
#pragma unroll
  for (int i = 0; i < 4; ++i) {
    const int row = m0 + wr * 64 + i * 16 + g * 4;
#pragma unroll
    for (int j = 0; j < NJ; ++j) {
      const int col = n0 + wc * 16 * NJ + j * 16 + r;
      const float bb = bias[col];
#pragma unroll
      for (int e = 0; e < 4; ++e) {
        const float v = acc[i][j][e] + bb;
        if (OUT_F32) ((float*)Cv)[(size_t)(row + e) * N + col] = v;
        else ((unsigned short*)Cv)[(size_t)(row + e) * N + col] = f2b(v);
      }
    }
  }
#undef STAGE_A
#undef STAGE_B
}

// ---------------- flash attention (causal, MQA) ----------------
// 32x32x16 MFMA, wave = 1 head x 32 q-rows (Q in regs). KVBLK=32, triple-
// buffered LDS (48KB), prefetch distance 2, counted vmcnt(4) (never 0
// mid-loop), raw s_barrier. Swapped QK^T -> per-lane scalar softmax -> P
// packed to PV A-frags via v_cvt_pk_bf16_f32 + shfl_xor(32). Conflict-free
// XOR swizzles on K and V (verified: PMC 0 conflicts at R9).

__global__ __launch_bounds__(256, 3)
void mqa_attn(const unsigned short* __restrict__ QKV,
              const unsigned short* __restrict__ Vt,
              const float* __restrict__ Kmax,
              unsigned short* __restrict__ Ob) {
  __shared__ __align__(16) char Ks[3][32 * 256];   // [kv row][16 slots], swz
  __shared__ __align__(16) char Vs[3][32 * 256];   // 4 d-rows/256B row, swz

  const int tid  = threadIdx.x;
  const int lane = tid & 63;
  const int wv   = tid >> 6;           // 0..3 (head within block)
  const int ln   = lane & 31;
  const int hi   = lane >> 5;
  const int x    = blockIdx.x;
  const int lo   = x & 255;
  const int b    = lo >> 7;
  const int hq   = (lo >> 5) & 3;
  const int qtl  = lo & 31;
  const int qt   = (x < 256) ? qtl : 63 - qtl;   // 0..63
  const int h    = hq * 4 + wv;
  const int qw   = qt * 32;
  const int nt   = qt + 1;             // KV tiles of 32

  // Q fragments (B-operand): lane holds Q[q=qw+ln][d = ch*16 + hi*8 + e]
  bf16x8 qf[8];
  {
    const unsigned short* qp =
        QKV + (size_t)(b * S_LEN + qw + ln) * NQKV + h * D_ + hi * 8;
#pragma unroll
    for (int ch = 0; ch < 8; ++ch) qf[ch] = *(const bf16x8*)(qp + ch * 16);
  }

  // Cauchy-Schwarz bound (exp2 domain), lane-uniform in q=ln.
  // Computed BEFORE staging so Q loads retire before the counted vmcnt.
  const float sscale = 0.08838834764831845f * 1.4426950408889634f;  // scale*log2e
  float qn2 = 0.f;
#pragma unroll
  for (int ch = 0; ch < 8; ++ch)
#pragma unroll
    for (int e = 0; e < 8; ++e) {
      const float qv = b2f((unsigned short)qf[ch][e]);
      qn2 += qv * qv;
    }
  qn2 += __shfl_xor(qn2, 32);
  const float m0c = sqrtf(qn2) * sqrtf(Kmax[b]) * sscale + 1.0f;

  const char* kbc = (const char*)(QKV + (size_t)(b * S_LEN) * NQKV + 2048);
  const char* vbc = (const char*)(Vt + (size_t)b * D_ * S_LEN);

  f32x16 acc[4] = {};
  float accl = 0.f;

  // ---- staging: K 512 chunks (32 rows x 16 slots) + V 512 chunks, 2 each/thr
  // V packing: LDS row vr holds d = vr*4+sub, 4 chunks of 16 kv-bytes each;
  // lin slot = sub*4 + q (q = 16B kv-chunk); stored slot = lin ^ (vr&15).
#define STAGE(bufi, t)                                                         \
  {                                                                            \
    const int kv0_ = (t) * 32;                                                 \
    _Pragma("unroll")                                                          \
    for (int i_ = 0; i_ < 2; ++i_) {                                           \
      const int ch_ = tid + 256 * i_;                                          \
      const int rr_ = ch_ >> 4;                                                \
      const int gk_ = (ch_ & 15) ^ (rr_ & 15);                                 \
      load_lds16(kbc + (size_t)(kv0_ + rr_) * (NQKV * 2) + gk_ * 16,           \
                 Ks[bufi] + ch_ * 16);                                         \
      const int gv_ = (ch_ & 15) ^ (rr_ & 15);                                 \
      const int vd_ = rr_ * 4 + (gv_ >> 2);                                    \
      load_lds16(vbc + (size_t)vd_ * (S_LEN * 2) + kv0_ * 2 + (gv_ & 3) * 16,  \
                 Vs[bufi] + ch_ * 16);                                         \
    }                                                                          \
  }

  __builtin_amdgcn_sched_barrier(0);
  STAGE(0, 0) STAGE(1, 1)
  asm volatile("s_waitcnt vmcnt(4)" ::: "memory");   // buf0 ready, buf1 in flight
  __builtin_amdgcn_s_barrier();
  __builtin_amdgcn_sched_barrier(0);

  for (int t = 0; t < nt; ++t) {
    const char* ksb = Ks[t % 3];
    const char* vsb = Vs[t % 3];
    const int kv0 = t * 32;
    const bool last = (t == nt - 1);
    const bool pf = (t + 2 < nt);
    if (pf) STAGE((t + 2) % 3, t + 2)

    // QK^T (swapped): S[kv][q]; A = K from LDS, B = Q regs
    f32x16 sA = {};
    __builtin_amdgcn_s_setprio(1);
#pragma unroll
    for (int ch = 0; ch < 8; ++ch) {
      const int slot0 = (2 * ch + hi) ^ (ln & 15);
      const bf16x8 kf0 = *(const bf16x8*)(ksb + ln * 256 + slot0 * 16);
      sA = mfma32(kf0, qf[ch], sA);
    }
    __builtin_amdgcn_s_setprio(0);

    // softmax (per-lane scalar; q = ln) + pack into PV A-frags, no LDS
    bf16x8 pa0, pa1;
    float p[16];
#pragma unroll
    for (int rr = 0; rr < 16; ++rr) {
      float e = sA[rr] * sscale - m0c;
      if (last) {
        const int kva = kv0 + (rr & 3) + 8 * (rr >> 2) + 4 * hi;
        e = (kva <= qw + ln) ? e : -__builtin_inff();
      }
      const float pv_ = __builtin_amdgcn_exp2f(e);
      p[rr] = pv_; accl += pv_;
    }
    {
      const unsigned int A0 = cvtpk(p[0], p[1]),   A1 = cvtpk(p[2], p[3]);
      const unsigned int B0 = cvtpk(p[4], p[5]),   B1 = cvtpk(p[6], p[7]);
      const unsigned int C0 = cvtpk(p[8], p[9]),   C1 = cvtpk(p[10], p[11]);
      const unsigned int D0 = cvtpk(p[12], p[13]), D1 = cvtpk(p[14], p[15]);
      unsigned int X0 = hi ? A0 : B0, X1 = hi ? A1 : B1;
      unsigned int Y0 = hi ? C0 : D0, Y1 = hi ? C1 : D1;
      X0 = (unsigned int)__shfl_xor((int)X0, 32);
      X1 = (unsigned int)__shfl_xor((int)X1, 32);
      Y0 = (unsigned int)__shfl_xor((int)Y0, 32);
      Y1 = (unsigned int)__shfl_xor((int)Y1, 32);
      union { unsigned int w[4]; bf16x8 v; } ua, ub;
      ua.w[0] = hi ? X0 : A0; ua.w[1] = hi ? X1 : A1;
      ua.w[2] = hi ? B0 : X0; ua.w[3] = hi ? B1 : X1;
      ub.w[0] = hi ? Y0 : C0; ub.w[1] = hi ? Y1 : C1;
      ub.w[2] = hi ? D0 : Y0; ub.w[3] = hi ? D1 : Y1;
      pa0 = ua.v; pa1 = ub.v;
    }

    // PV: acc[dt] += P(32q x 32kv) * V(32kv x 32d); B = V from LDS
    __builtin_amdgcn_s_setprio(1);
#pragma unroll
    for (int dt = 0; dt < 4; ++dt) {
      const int vr = dt * 8 + (ln >> 2);
      const char* base = vsb + vr * 256;
      const int sl0 = (((ln & 3) << 2) + hi) ^ (vr & 15);
      acc[dt] = mfma32(pa0, *(const bf16x8*)(base + sl0 * 16), acc[dt]);
      const int sl1 = (((ln & 3) << 2) + 2 + hi) ^ (vr & 15);
      acc[dt] = mfma32(pa1, *(const bf16x8*)(base + sl1 * 16), acc[dt]);
    }
    __builtin_amdgcn_s_setprio(0);

    // ---- tile boundary: publish buf t+1 (counted vmcnt) ----
    if (t + 1 < nt) {
      if (pf) { asm volatile("s_waitcnt vmcnt(4)" ::: "memory"); }
      else    { asm volatile("s_waitcnt vmcnt(0)" ::: "memory"); }
      __builtin_amdgcn_s_barrier();
      __builtin_amdgcn_sched_barrier(0);
    }
  }

  // epilogue: full row-sum, per-reg 1/l via shfl, store bf16
  const float lf = accl + __shfl_xor(accl, 32);
  const float linv = 1.0f / lf;
  unsigned short* ob = Ob + (size_t)(b * S_LEN + qw) * HID_ + h * D_ + ln;
#pragma unroll
  for (int rr = 0; rr < 16; ++rr) {
    const int qr = (rr & 3) + 8 * (rr >> 2) + 4 * hi;
    const float li = __shfl(linv, qr);
#pragma unroll
    for (int dt = 0; dt < 4; ++dt)
      ob[(size_t)qr * HID_ + dt * 32] = f2b(acc[dt][rr] * li);
  }
#undef STAGE
}

// ---------------- launcher ----------------

extern "C" void kernel_launch(void* const* d_in, const int* in_sizes, int n_in,
                              void* d_out, int out_size, void* d_ws, size_t ws_size,
                              hipStream_t stream) {
  (void)in_sizes; (void)n_in; (void)out_size; (void)ws_size;
  const float* x  = (const float*)d_in[0];
  const float* Wq = (const float*)d_in[2];
  const float* bq = (const float*)d_in[3];
  const float* Wk = (const float*)d_in[4];
  const float* bk = (const float*)d_in[5];
  const float* Wv = (const float*)d_in[6];
  const float* bv = (const float*)d_in[7];
  const float* Wo = (const float*)d_in[8];
  const float* bo = (const float*)d_in[9];
  float* out = (float*)d_out;

  char* p = (char*)d_ws;
  unsigned short* xb   = (unsigned short*)p;  p += (size_t)4096 * 2048 * 2;
  unsigned short* Wcat = (unsigned short*)p;  p += (size_t)2304 * 2048 * 2;
  float*          bcat = (float*)p;           p += 16384;
  unsigned short* Wob  = (unsigned short*)p;  p += (size_t)2048 * 2048 * 2;
  unsigned short* QKV  = (unsigned short*)p;  p += (size_t)4096 * 2304 * 2;
  unsigned short* Vt   = (unsigned short*)p;  p += (size_t)2 * 128 * 2048 * 2;
  float*          Kmax = (float*)p;           p += 64;
  unsigned short* Ob   = xb;  // xb dead after gemm1

  cast_f32_bf16_k<<<8192, 256, 0, stream>>>(x, xb, 2097152);
  build_wcat_k<<<4608, 256, 0, stream>>>(Wq, Wk, Wv, bq, bk, bv, Wcat, bcat, Kmax);
  cast_f32_bf16_k<<<4096, 256, 0, stream>>>(Wo, Wob, 1048576);
  gemm_nt2<0, 3><<<384, 512, 0, stream>>>(xb, Wcat, bcat, QKV, 2304, 2048);
  transpose_v<<<dim3(32, 2), 256, 0, stream>>>(QKV, Vt);
  kmax_k<<<16, 256, 0, stream>>>(QKV, Kmax);
  mqa_attn<<<512, 256, 0, stream>>>(QKV, Vt, Kmax, Ob);
  gemm_nt2<1, 4><<<256, 512, 0, stream>>>(Ob, Wob, bo, out, 2048, 2048);
}

// Round 11
// 191.225 us; speedup vs baseline: 1.1305x; 1.1305x over previous
//
#include <hip/hip_runtime.h>

// MQA: B=2, S=2048, HID=2048, H=16, D=128 (single KV head), causal.
// Pipeline: cast -> fused QKV NT-GEMM (pipelined, counted-vmcnt) -> V
//           transpose -> kmax -> flash attention (32x32x16, in-register P,
//           KVBLK=64 dbuf, SPLIT-KV for qt>=32 with additive partials) ->
//           combine -> out NT-GEMM (pipelined).

#define S_LEN 2048
#define HID_  2048
#define D_    128
#define NQKV  2304   // 2048 Q + 128 K + 128 V columns

typedef __attribute__((ext_vector_type(8))) short bf16x8;
typedef __attribute__((ext_vector_type(4))) float f32x4;
typedef __attribute__((ext_vector_type(16))) float f32x16;

__device__ __forceinline__ unsigned short f2b(float f) {
  union { float f; unsigned int u; } a; a.f = f;
  unsigned int u = a.u;
  return (unsigned short)((u + 0x7fffu + ((u >> 16) & 1u)) >> 16);  // RNE
}

__device__ __forceinline__ float b2f(unsigned short s) {
  union { unsigned int u; float f; } a; a.u = ((unsigned int)s) << 16;
  return a.f;
}

__device__ __forceinline__ void load_lds16(const void* g, void* l) {
  __builtin_amdgcn_global_load_lds(
      (const __attribute__((address_space(1))) void*)g,
      (__attribute__((address_space(3))) void*)l, 16, 0, 0);
}

__device__ __forceinline__ f32x4 mfma16(bf16x8 a, bf16x8 b, f32x4 c) {
  return __builtin_amdgcn_mfma_f32_16x16x32_bf16(a, b, c, 0, 0, 0);
}

__device__ __forceinline__ f32x16 mfma32(bf16x8 a, bf16x8 b, f32x16 c) {
  return __builtin_amdgcn_mfma_f32_32x32x16_bf16(a, b, c, 0, 0, 0);
}

__device__ __forceinline__ unsigned int cvtpk(float lo, float hi) {
  unsigned int r;
  asm volatile("v_cvt_pk_bf16_f32 %0, %1, %2" : "=v"(r) : "v"(lo), "v"(hi));
  return r;
}

// ---------------- casts / packing ----------------

__global__ void cast_f32_bf16_k(const float* __restrict__ in,
                                unsigned short* __restrict__ out, int n4) {
  const int idx = blockIdx.x * 256 + threadIdx.x;
  if (idx < n4) {
    const float4 v = ((const float4*)in)[idx];
    ushort4 o;
    o.x = f2b(v.x); o.y = f2b(v.y); o.z = f2b(v.z); o.w = f2b(v.w);
    ((ushort4*)out)[idx] = o;
  }
}

__global__ void build_wcat_k(const float* __restrict__ Wq,
                             const float* __restrict__ Wk,
                             const float* __restrict__ Wv,
                             const float* __restrict__ bq,
                             const float* __restrict__ bk,
                             const float* __restrict__ bv,
                             unsigned short* __restrict__ Wcat,
                             float* __restrict__ bcat,
                             float* __restrict__ Kmax) {
  const int idx = blockIdx.x * 256 + threadIdx.x;
  const int i = idx * 4;
  const int row = i >> 11;
  const int col = i & 2047;
  const float* src;
  if (row < 2048)      src = Wq + (size_t)row * 2048 + col;
  else if (row < 2176) src = Wk + (size_t)(row - 2048) * 2048 + col;
  else                 src = Wv + (size_t)(row - 2176) * 2048 + col;
  const float4 v = *(const float4*)src;
  ushort4 o;
  o.x = f2b(v.x); o.y = f2b(v.y); o.z = f2b(v.z); o.w = f2b(v.w);
  *(ushort4*)(Wcat + i) = o;
  if (idx < NQKV)
    bcat[idx] = (idx < 2048) ? bq[idx] : (idx < 2176) ? bk[idx - 2048] : bv[idx - 2176];
  if (idx < 2) Kmax[idx] = 0.f;   // re-init every launch (runs before kmax_k)
}

// Vt[b][d][s] = QKV[b*S+s][2176+d] -- LDS-tiled transpose
__global__ __launch_bounds__(256)
void transpose_v(const unsigned short* __restrict__ QKV,
                 unsigned short* __restrict__ Vt) {
  __shared__ unsigned short tile[64][136];
  const int tid = threadIdx.x;
  const int s0  = blockIdx.x * 64;
  const int b   = blockIdx.y;
  const int row = tid >> 2;
  const int cb  = (tid & 3) * 32;
  const unsigned short* src = QKV + (size_t)(b * S_LEN + s0 + row) * NQKV + 2176 + cb;
#pragma unroll
  for (int i = 0; i < 4; ++i)
    *(bf16x8*)&tile[row][cb + i * 8] = *(const bf16x8*)(src + i * 8);
  __syncthreads();
  const int d  = tid >> 1;
  const int sc = (tid & 1) * 32;
  unsigned short* dst = Vt + ((size_t)b * D_ + d) * S_LEN + s0 + sc;
#pragma unroll
  for (int i = 0; i < 4; ++i) {
    bf16x8 vv;
#pragma unroll
    for (int e = 0; e < 8; ++e) vv[e] = tile[sc + i * 8 + e][d];
    *(bf16x8*)(dst + i * 8) = vv;
  }
}

// max_s ||k[b,s]||^2 -> Kmax[b] (as float bits via atomicMax on uint)
__global__ __launch_bounds__(256)
void kmax_k(const unsigned short* __restrict__ QKV, float* __restrict__ Kmax) {
  __shared__ float red[256];
  const int tid = threadIdx.x;
  const int b = blockIdx.x >> 3;
  const int s = (blockIdx.x & 7) * 256 + tid;
  const unsigned short* kp = QKV + (size_t)(b * S_LEN + s) * NQKV + 2048;
  float sum = 0.f;
#pragma unroll
  for (int i = 0; i < 16; ++i) {
    bf16x8 v = *(const bf16x8*)(kp + i * 8);
#pragma unroll
    for (int e = 0; e < 8; ++e) { const float f = b2f((unsigned short)v[e]); sum += f * f; }
  }
  red[tid] = sum;
  __syncthreads();
  for (int off = 128; off > 0; off >>= 1) {
    if (tid < off) red[tid] = fmaxf(red[tid], red[tid + off]);
    __syncthreads();
  }
  if (tid == 0) atomicMax((unsigned int*)(Kmax + b), __float_as_uint(red[0]));
}

// ---------------- pipelined NT GEMM (unchanged from R8/R9) ----------------

template <int OUT_F32, int NJ>
__global__ __launch_bounds__(512, 2)
void gemm_nt2(const unsigned short* __restrict__ A,
              const unsigned short* __restrict__ Bm,
              const float* __restrict__ bias,
              void* __restrict__ Cv,
              int N, int K) {
  constexpr int BN = 64 * NJ;
  __shared__ __align__(16) char As[3][128 * 128];   // [buf][row<<7 | slot*16]
  __shared__ __align__(16) char Bs[3][BN * 128];

  const int tid  = threadIdx.x;
  const int lane = tid & 63;
  const int wv   = tid >> 6;
  const int wr   = wv >> 2;        // 0..1
  const int wc   = wv & 3;         // 0..3
  const int g    = lane >> 4, r = lane & 15;

  const int nwg  = gridDim.x;
  const int bid  = blockIdx.x;
  const int sbid = (bid & 7) * (nwg >> 3) + (bid >> 3);   // XCD-chunked
  const int nx   = N / BN;
  const int m0   = (sbid / nx) * 128;
  const int n0   = (sbid % nx) * BN;
  const int NT   = K >> 6;

  const size_t Kb = (size_t)K * 2;
  const char* Ab = (const char*)A + (size_t)m0 * Kb;
  const char* Bb = (const char*)Bm + (size_t)n0 * Kb;

#define STAGE_A(bufi, t)                                                       \
  {                                                                            \
    const int kb_ = (t) * 128;                                                 \
    _Pragma("unroll")                                                          \
    for (int i_ = 0; i_ < 2; ++i_) {                                           \
      const int ch_ = tid + 512 * i_;                                          \
      const int rr_ = ch_ >> 3;                                                \
      const int sl_ = (ch_ & 7) ^ (rr_ & 7);                                   \
      load_lds16(Ab + (size_t)rr_ * Kb + kb_ + sl_ * 16, As[bufi] + ch_ * 16); \
    }                                                                          \
  }
#define STAGE_B(bufi, t)                                                       \
  {                                                                            \
    const int kb_ = (t) * 128;                                                 \
    _Pragma("unroll")                                                          \
    for (int i_ = 0; i_ < NJ; ++i_) {                                          \
      const int ch_ = tid + 512 * i_;                                          \
      const int rr_ = ch_ >> 3;                                                \
      const int sl_ = (ch_ & 7) ^ (rr_ & 7);                                   \
      load_lds16(Bb + (size_t)rr_ * Kb + kb_ + sl_ * 16, Bs[bufi] + ch_ * 16); \
    }                                                                          \
  }

  f32x4 acc[4][NJ] = {};
  const int s0 = ((g ^ (r & 7)) << 4);           // kk=0 slot byte
  const int s1 = (((4 | g) ^ (r & 7)) << 4);     // kk=1 slot byte

  STAGE_A(0, 0) STAGE_B(0, 0) STAGE_A(1, 1) STAGE_B(1, 1)

  // publish buf0 before the t=0 reads (R8 fix)
  asm volatile("s_waitcnt vmcnt(%0)" :: "i"(NJ + 2) : "memory");
  __builtin_amdgcn_s_barrier();
  __builtin_amdgcn_sched_barrier(0);

  for (int t = 0; t < NT; ++t) {
    const char* as = As[t % 3];
    const char* bs = Bs[t % 3];
    const int nb = (t + 2) % 3;
    const bool pf = (t + 2 < NT);

    bf16x8 af[4], bfr[NJ];
    // ---- phase 0 (kk = 0) ----
#pragma unroll
    for (int i = 0; i < 4; ++i)
      af[i] = *(const bf16x8*)(as + ((wr * 64 + i * 16 + r) << 7) + s0);
#pragma unroll
    for (int j = 0; j < NJ; ++j)
      bfr[j] = *(const bf16x8*)(bs + ((wc * 16 * NJ + j * 16 + r) << 7) + s0);
    if (pf) STAGE_A(nb, t + 2)
    __builtin_amdgcn_s_barrier();
    __builtin_amdgcn_sched_barrier(0);
    asm volatile("s_waitcnt lgkmcnt(0)" ::: "memory");
    __builtin_amdgcn_sched_barrier(0);
    __builtin_amdgcn_s_setprio(1);
#pragma unroll
    for (int i = 0; i < 4; ++i)
#pragma unroll
      for (int j = 0; j < NJ; ++j)
        acc[i][j] = mfma16(af[i], bfr[j], acc[i][j]);
    __builtin_amdgcn_s_setprio(0);
    __builtin_amdgcn_sched_barrier(0);

    // ---- phase 1 (kk = 1) ----
#pragma unroll
    for (int i = 0; i < 4; ++i)
      af[i] = *(const bf16x8*)(as + ((wr * 64 + i * 16 + r) << 7) + s1);
#pragma unroll
    for (int j = 0; j < NJ; ++j)
      bfr[j] = *(const bf16x8*)(bs + ((wc * 16 * NJ + j * 16 + r) << 7) + s1);
    if (pf) STAGE_B(nb, t + 2)
    __builtin_amdgcn_s_barrier();
    __builtin_amdgcn_sched_barrier(0);
    asm volatile("s_waitcnt lgkmcnt(0)" ::: "memory");
    __builtin_amdgcn_sched_barrier(0);
    __builtin_amdgcn_s_setprio(1);
#pragma unroll
    for (int i = 0; i < 4; ++i)
#pragma unroll
      for (int j = 0; j < NJ; ++j)
        acc[i][j] = mfma16(af[i], bfr[j], acc[i][j]);
    __builtin_amdgcn_s_setprio(0);

    // ---- tile boundary: publish buf t+1 (counted vmcnt, never 0 mid-loop) --
    if (pf) { asm volatile("s_waitcnt vmcnt(%0)" :: "i"(NJ + 2) : "memory"); }
    else    { asm volatile("s_waitcnt vmcnt(0)" ::: "memory"); }
    __builtin_amdgcn_s_barrier();
    __builtin_amdgcn_sched_barrier(0);
  }

  // epilogue
#pragma unroll
  for (int i = 0; i < 4; ++i) {
    const int row = m0 + wr * 64 + i * 16 + g * 4;
#pragma unroll
    for (int j = 0; j < NJ; ++j) {
      const int col = n0 + wc * 16 * NJ + j * 16 + r;
      const float bb = bias[col];
#pragma unroll
      for (int e = 0; e < 4; ++e) {
        const float v = acc[i][j][e] + bb;
        if (OUT_F32) ((float*)Cv)[(size_t)(row + e) * N + col] = v;
        else ((unsigned short*)Cv)[(size_t)(row + e) * N + col] = f2b(v);
      }
    }
  }
#undef STAGE_A
#undef STAGE_B
}

// ---------------- flash attention (causal, MQA, split-KV) ----------------
// R9 per-tile structure (KVBLK=64, dbuf, __syncthreads -- measured best).
// Fixed-m0 Cauchy softmax => partials over disjoint KV ranges are ADDITIVE.
// qt>=32 split into chunk0 = tiles [0,16) (no diagonal) and chunk1 = [16,nt);
// both write raw bf16 acc + f32 row-sum partials; combine_k merges.
// Grid 768 blocks, largest chunks first; 64KB LDS -> 2 blocks/CU + backfill.

__global__ __launch_bounds__(256, 2)
void mqa_attn(const unsigned short* __restrict__ QKV,
              const unsigned short* __restrict__ Vt,
              const float* __restrict__ Kmax,
              unsigned short* __restrict__ Ob,
              unsigned short* __restrict__ Pacc,
              float* __restrict__ Pl) {
  __shared__ __align__(16) char Ks[2][64 * 256];
  __shared__ __align__(16) char Vs[2][64 * 256];

  const int tid  = threadIdx.x;
  const int lane = tid & 63;
  const int wv   = tid >> 6;           // 0..3 (head within block)
  const int ln   = lane & 31;
  const int hi   = lane >> 5;
  const int x    = blockIdx.x;         // 0..767
  const int bhq  = x & 7;
  const int b    = bhq >> 2;
  const int hq   = bhq & 3;
  const int widx = x >> 3;             // 0..95, largest work first
  int qt, t0, te, chunk;
  if (widx < 32)      { qt = 32 + widx; t0 = 0;  te = 16;         chunk = 0; }
  else if (widx < 64) { qt = 95 - widx; t0 = 16; te = qt / 2 + 1; chunk = 1; }
  else                { qt = 95 - widx; t0 = 0;  te = qt / 2 + 1; chunk = -1; }
  const int h    = hq * 4 + wv;
  const int qw   = qt * 32;
  const int lastT = qt / 2;            // index of the diagonal tile

  // Q fragments (B-operand): lane holds Q[q=qw+ln][d = ch*16 + hi*8 + e]
  bf16x8 qf[8];
  {
    const unsigned short* qp =
        QKV + (size_t)(b * S_LEN + qw + ln) * NQKV + h * D_ + hi * 8;
#pragma unroll
    for (int ch = 0; ch < 8; ++ch) qf[ch] = *(const bf16x8*)(qp + ch * 16);
  }

  // Cauchy-Schwarz bound (exp2 domain), lane-uniform in q=ln -- FIXED m0,
  // which is what makes split-KV partials exactly additive.
  const float sscale = 0.08838834764831845f * 1.4426950408889634f;  // scale*log2e
  float qn2 = 0.f;
#pragma unroll
  for (int ch = 0; ch < 8; ++ch)
#pragma unroll
    for (int e = 0; e < 8; ++e) {
      const float qv = b2f((unsigned short)qf[ch][e]);
      qn2 += qv * qv;
    }
  qn2 += __shfl_xor(qn2, 32);
  const float m0c = sqrtf(qn2) * sqrtf(Kmax[b]) * sscale + 1.0f;

  const char* kbc = (const char*)(QKV + (size_t)(b * S_LEN) * NQKV + 2048);
  const char* vbc = (const char*)(Vt + (size_t)b * D_ * S_LEN);

  f32x16 acc[4] = {};
  float accl = 0.f;

#define STAGE(bufi, t)                                                         \
  {                                                                            \
    const int kv0_ = (t) * 64;                                                 \
    _Pragma("unroll")                                                          \
    for (int i_ = 0; i_ < 4; ++i_) {                                           \
      const int ch_ = tid + 256 * i_;                                          \
      const int kr_ = ch_ >> 4;                                                \
      const int kg_ = (ch_ & 15) ^ (kr_ & 15);                                 \
      load_lds16(kbc + (size_t)(kv0_ + kr_) * (NQKV * 2) + kg_ * 16,           \
                 Ks[bufi] + ch_ * 16);                                         \
      const int vg_ = (ch_ & 15) ^ (kr_ & 15);                                 \
      const int vd_ = kr_ * 2 + (vg_ >> 3);                                    \
      load_lds16(vbc + (size_t)vd_ * (S_LEN * 2) + kv0_ * 2 + (vg_ & 7) * 16,  \
                 Vs[bufi] + ch_ * 16);                                         \
    }                                                                          \
  }

  STAGE(0, t0);
  int cur = 0;

  for (int t = t0; t < te; ++t) {
    __syncthreads();
    if (t + 1 < te) STAGE(cur ^ 1, t + 1);

    const char* ksb = Ks[cur];
    const char* vsb = Vs[cur];
    const int kv0 = t * 64;
    const bool last = (t == lastT);
    const bool doUp = (kv0 + 32 <= qw + 31);
    cur ^= 1;

    f32x16 sA = {}, sB = {};
    __builtin_amdgcn_s_setprio(1);
#pragma unroll
    for (int ch = 0; ch < 8; ++ch) {
      const int slot0 = (2 * ch + hi) ^ (ln & 15);
      const bf16x8 kf0 = *(const bf16x8*)(ksb + ln * 256 + slot0 * 16);
      sA = mfma32(kf0, qf[ch], sA);
      if (doUp) {
        const bf16x8 kf1 = *(const bf16x8*)(ksb + (32 + ln) * 256 + slot0 * 16);
        sB = mfma32(kf1, qf[ch], sB);
      }
    }
    __builtin_amdgcn_s_setprio(0);

    bf16x8 pa0, pa1, pa2, pa3;
    float p[16];

#define SOFTMAX(sv, kvtbase)                                                   \
    _Pragma("unroll")                                                          \
    for (int rr = 0; rr < 16; ++rr) {                                          \
      float e = sv[rr] * sscale - m0c;                                         \
      if (last) {                                                              \
        const int kva = (kvtbase) + (rr & 3) + 8 * (rr >> 2) + 4 * hi;         \
        e = (kva <= qw + ln) ? e : -__builtin_inff();                          \
      }                                                                        \
      const float pv_ = __builtin_amdgcn_exp2f(e);                             \
      p[rr] = pv_; accl += pv_;                                                \
    }

#define PACK2(fa, fb)                                                          \
    {                                                                          \
      const unsigned int A0 = cvtpk(p[0], p[1]),   A1 = cvtpk(p[2], p[3]);     \
      const unsigned int B0 = cvtpk(p[4], p[5]),   B1 = cvtpk(p[6], p[7]);     \
      const unsigned int C0 = cvtpk(p[8], p[9]),   C1 = cvtpk(p[10], p[11]);   \
      const unsigned int D0 = cvtpk(p[12], p[13]), D1 = cvtpk(p[14], p[15]);   \
      unsigned int X0 = hi ? A0 : B0, X1 = hi ? A1 : B1;                       \
      unsigned int Y0 = hi ? C0 : D0, Y1 = hi ? C1 : D1;                       \
      X0 = (unsigned int)__shfl_xor((int)X0, 32);                              \
      X1 = (unsigned int)__shfl_xor((int)X1, 32);                              \
      Y0 = (unsigned int)__shfl_xor((int)Y0, 32);                              \
      Y1 = (unsigned int)__shfl_xor((int)Y1, 32);                              \
      union { unsigned int w[4]; bf16x8 v; } ua, ub;                           \
      ua.w[0] = hi ? X0 : A0; ua.w[1] = hi ? X1 : A1;                          \
      ua.w[2] = hi ? B0 : X0; ua.w[3] = hi ? B1 : X1;                          \
      ub.w[0] = hi ? Y0 : C0; ub.w[1] = hi ? Y1 : C1;                          \
      ub.w[2] = hi ? D0 : Y0; ub.w[3] = hi ? D1 : Y1;                          \
      fa = ua.v; fb = ub.v;                                                    \
    }

    SOFTMAX(sA, kv0)
    PACK2(pa0, pa1)
    if (doUp) {
      SOFTMAX(sB, kv0 + 32)
      PACK2(pa2, pa3)
    }

    __builtin_amdgcn_s_setprio(1);
#pragma unroll
    for (int dt = 0; dt < 4; ++dt) {
      const int vrow = dt * 16 + (ln >> 1);
      const int gb   = (ln & 1) << 3;
      {
        const int sl = (gb + 0 + hi) ^ (vrow & 15);
        const bf16x8 vf = *(const bf16x8*)(vsb + vrow * 256 + sl * 16);
        acc[dt] = mfma32(pa0, vf, acc[dt]);
      }
      {
        const int sl = (gb + 2 + hi) ^ (vrow & 15);
        const bf16x8 vf = *(const bf16x8*)(vsb + vrow * 256 + sl * 16);
        acc[dt] = mfma32(pa1, vf, acc[dt]);
      }
      if (doUp) {
        {
          const int sl = (gb + 4 + hi) ^ (vrow & 15);
          const bf16x8 vf = *(const bf16x8*)(vsb + vrow * 256 + sl * 16);
          acc[dt] = mfma32(pa2, vf, acc[dt]);
        }
        {
          const int sl = (gb + 6 + hi) ^ (vrow & 15);
          const bf16x8 vf = *(const bf16x8*)(vsb + vrow * 256 + sl * 16);
          acc[dt] = mfma32(pa3, vf, acc[dt]);
        }
      }
    }
    __builtin_amdgcn_s_setprio(0);
#undef SOFTMAX
#undef PACK2
  }

  const float lf = accl + __shfl_xor(accl, 32);   // full row-sum for q = ln

  if (chunk < 0) {
    // unsplit: normalize and store final bf16
    const float linv = 1.0f / lf;
    unsigned short* ob = Ob + (size_t)(b * S_LEN + qw) * HID_ + h * D_ + ln;
#pragma unroll
    for (int rr = 0; rr < 16; ++rr) {
      const int qr = (rr & 3) + 8 * (rr >> 2) + 4 * hi;
      const float li = __shfl(linv, qr);
#pragma unroll
      for (int dt = 0; dt < 4; ++dt)
        ob[(size_t)qr * HID_ + dt * 32] = f2b(acc[dt][rr] * li);
    }
  } else {
    // split: raw bf16 partial acc + f32 row-sum
    const int slot = ((chunk * 2 + b) * 16 + h) * 32 + (qt - 32);
    unsigned short* pa = Pacc + (size_t)slot * 32 * 128 + ln;
#pragma unroll
    for (int rr = 0; rr < 16; ++rr) {
      const int qr = (rr & 3) + 8 * (rr >> 2) + 4 * hi;
#pragma unroll
      for (int dt = 0; dt < 4; ++dt)
        pa[qr * 128 + dt * 32] = f2b(acc[dt][rr]);
    }
    if (hi == 0) Pl[slot * 32 + ln] = lf;
  }
#undef STAGE
}

// combine: out = (A0 + A1) / (L0 + L1) for all split (b,h,qt>=32)
__global__ __launch_bounds__(256)
void combine_k(const unsigned short* __restrict__ Pacc,
               const float* __restrict__ Pl,
               unsigned short* __restrict__ Ob) {
  const int x  = blockIdx.x;           // 1024 = b(2) x h(16) x qs(32)
  const int qs = x & 31;
  const int h  = (x >> 5) & 15;
  const int b  = x >> 9;
  const int tid = threadIdx.x;
  const int q  = tid >> 3;             // 0..31
  const int dp = (tid & 7) * 16;       // 0..112
  const int s0 = (b * 16 + h) * 32 + qs;
  const int s1 = ((2 + b) * 16 + h) * 32 + qs;
  const float inv = 1.0f / (Pl[s0 * 32 + q] + Pl[s1 * 32 + q]);
  const unsigned short* a0 = Pacc + ((size_t)s0 * 32 + q) * 128 + dp;
  const unsigned short* a1 = Pacc + ((size_t)s1 * 32 + q) * 128 + dp;
  unsigned short* ob =
      Ob + (size_t)(b * S_LEN + (32 + qs) * 32 + q) * HID_ + h * D_ + dp;
  const bf16x8 v0a = *(const bf16x8*)a0, v0b = *(const bf16x8*)(a0 + 8);
  const bf16x8 v1a = *(const bf16x8*)a1, v1b = *(const bf16x8*)(a1 + 8);
  bf16x8 oa, obv;
#pragma unroll
  for (int e = 0; e < 8; ++e) {
    oa[e]  = (short)f2b((b2f((unsigned short)v0a[e]) + b2f((unsigned short)v1a[e])) * inv);
    obv[e] = (short)f2b((b2f((unsigned short)v0b[e]) + b2f((unsigned short)v1b[e])) * inv);
  }
  *(bf16x8*)ob = oa;
  *(bf16x8*)(ob + 8) = obv;
}

// ---------------- launcher ----------------

extern "C" void kernel_launch(void* const* d_in, const int* in_sizes, int n_in,
                              void* d_out, int out_size, void* d_ws, size_t ws_size,
                              hipStream_t stream) {
  (void)in_sizes; (void)n_in; (void)out_size; (void)ws_size;
  const float* x  = (const float*)d_in[0];
  const float* Wq = (const float*)d_in[2];
  const float* bq = (const float*)d_in[3];
  const float* Wk = (const float*)d_in[4];
  const float* bk = (const float*)d_in[5];
  const float* Wv = (const float*)d_in[6];
  const float* bv = (const float*)d_in[7];
  const float* Wo = (const float*)d_in[8];
  const float* bo = (const float*)d_in[9];
  float* out = (float*)d_out;

  char* p = (char*)d_ws;
  unsigned short* xb   = (unsigned short*)p;  p += (size_t)4096 * 2048 * 2;
  unsigned short* Wcat = (unsigned short*)p;  p += (size_t)2304 * 2048 * 2;
  float*          bcat = (float*)p;           p += 16384;
  unsigned short* Wob  = (unsigned short*)p;  p += (size_t)2048 * 2048 * 2;
  unsigned short* QKV  = (unsigned short*)p;  p += (size_t)4096 * 2304 * 2;
  unsigned short* Vt   = (unsigned short*)p;  p += (size_t)2 * 128 * 2048 * 2;
  float*          Kmax = (float*)p;           p += 64;
  unsigned short* Pacc = (unsigned short*)p;  p += (size_t)2048 * 32 * 128 * 2; // 16.8MB
  float*          Pl   = (float*)p;           p += (size_t)2048 * 32 * 4;       // 256KB
  unsigned short* Ob   = xb;  // xb dead after gemm1

  cast_f32_bf16_k<<<8192, 256, 0, stream>>>(x, xb, 2097152);
  build_wcat_k<<<4608, 256, 0, stream>>>(Wq, Wk, Wv, bq, bk, bv, Wcat, bcat, Kmax);
  cast_f32_bf16_k<<<4096, 256, 0, stream>>>(Wo, Wob, 1048576);
  gemm_nt2<0, 3><<<384, 512, 0, stream>>>(xb, Wcat, bcat, QKV, 2304, 2048);
  transpose_v<<<dim3(32, 2), 256, 0, stream>>>(QKV, Vt);
  kmax_k<<<16, 256, 0, stream>>>(QKV, Kmax);
  mqa_attn<<<768, 256, 0, stream>>>(QKV, Vt, Kmax, Ob, Pacc, Pl);
  combine_k<<<1024, 256, 0, stream>>>(Pacc, Pl, Ob);
  gemm_nt2<1, 4><<<256, 512, 0, stream>>>(Ob, Wob, bo, out, 2048, 2048);
}